// Round 10
// baseline (67.383 us; speedup 1.0000x reference)
//
#include <hip/hip_runtime.h>

#define MT    132      // padded (M+1): 129 valid + 3 zero pad
#define NSEQ  512
#define LSEQ  256
#define MM    128      // M
#define NROW  129      // M+1
#define BETA  10.0     // reweighting: track a * e^{BETA*(t - mp)}
#define LOG2E 1.4426950408889634
#define LN2   0.6931471805599453

// per-mp transition tables (indexed by i = chain/source index), REWEIGHTED
enum { T_TMX=0, T_TIX, T_TMEQ0, T_TIEQ0, T_TMEQ1, T_TIEQ1,
       T_ENT0, T_ENT1, T_STP, T_I0, T_I1, T_COUNT };          // 11

// ws layout: [int tokoff NSEQ*LSEQ] [tabd doubles] [emd doubles, 16B-aligned]
#define TOKI_BYTES (NSEQ*LSEQ*4)          // 524288
#define TABD_OFF   TOKI_BYTES
#define TABD_CNT   (T_COUNT*MT)           // 1452 doubles
#define EMD_OFF    (TABD_OFF + TABD_CNT*8) // 16-aligned
#define EMD_ROW_B  (MT*16)                // 2112 bytes per token row (col pairs)

// DPP ctrl encodings (gfx9/CDNA): ROW_SHR:d = 0x110+d, WAVE_SHR1 = 0x138,
// ROW_BCAST15 = 0x142, ROW_BCAST31 = 0x143.  (HW-verified rounds 4/7/8.)
template <int CTRL, int RMASK, bool BC>
__device__ __forceinline__ double dpp_d(double v) {
  int lo = __double2loint(v), hi = __double2hiint(v);
  lo = __builtin_amdgcn_update_dpp(0, lo, CTRL, RMASK, 0xF, BC);
  hi = __builtin_amdgcn_update_dpp(0, hi, CTRL, RMASK, 0xF, BC);
  return __hiloint2double(hi, lo);
}

__device__ __forceinline__ double lse2d(double a, double b) {
  double m = fmax(a, b);
  return m + log(exp(a - m) + exp(b - m));
}

// ---------------------------------------------------------- prep + tok ----
__global__ void prep_tok_kernel(const float* __restrict__ anc,
                                const float* __restrict__ insq,
                                const float* __restrict__ rr,
                                const float* __restrict__ uu,
                                const float* __restrict__ data,
                                double* __restrict__ tabd,
                                double* __restrict__ emd,
                                int* __restrict__ tokoff) {
  const int tid = threadIdx.x;
  if (blockIdx.x != 0) {
    // ---- token decode: one thread per position, float4 loads ----
    const int n = blockIdx.x - 1;
    const float4* p = (const float4*)(data + (size_t)(n*LSEQ + tid)*24);
    int tok = 24;
#pragma unroll
    for (int q = 0; q < 6; ++q) {
      float4 v = p[q];
      if (v.x > 0.5f) tok = 4*q+0;
      if (v.y > 0.5f) tok = 4*q+1;
      if (v.z > 0.5f) tok = 4*q+2;
      if (v.w > 0.5f) tok = 4*q+3;
    }
    tokoff[n*LSEQ + tid] = tok * EMD_ROW_B;   // byte offset of token row
    return;
  }

  // ---- block 0: tables ----
  __shared__ double ls[T_COUNT*MT];
  if (tid < MT) {
    double v[T_COUNT];
#pragma unroll
    for (int k = 0; k < T_COUNT; ++k) v[k] = 0.0;
    if (tid <= MM) {
      const int m = tid;
      double rn[3][2], un[3][2];
#pragma unroll
      for (int j = 0; j < 3; ++j) {
        double a0 = (double)rr[(m*3+j)*2+0], a1 = (double)rr[(m*3+j)*2+1];
        double l  = lse2d(a0, a1);
        rn[j][0] = a0 - l; rn[j][1] = a1 - l;
        double b0 = (double)uu[(m*3+j)*2+0], b1 = (double)uu[(m*3+j)*2+1];
        double l2 = lse2d(b0, b1);
        un[j][0] = b0 - l2; un[j][1] = b1 - l2;
      }
      v[T_TMX]   = exp(rn[0][0] + un[0][1] - BETA);  // match exit -> chain  (x e^-B)
      v[T_TIX]   = exp(rn[1][0] + un[1][1]);         // insert exit -> chain
      v[T_TMEQ0] = exp(rn[0][0] + un[0][0]);         // match -> (i,0)
      v[T_TIEQ0] = exp(rn[1][0] + un[1][0] + BETA);  // insert -> (i,0)      (x e^+B)
      v[T_TMEQ1] = exp(rn[0][1]);                    // match -> (i,1)
      v[T_TIEQ1] = exp(rn[1][1] + BETA);             // insert -> (i,1)      (x e^+B)
      v[T_ENT0]  = exp(rn[2][0] + un[2][0]);         // chain -> (mp,0)
      v[T_ENT1]  = exp(rn[2][1]);                    // chain -> (mp,1)
      v[T_STP]   = exp(rn[2][0] + un[2][1] - BETA);  // chain continue       (x e^-B)
    }
#pragma unroll
    for (int k = 0; k < T_COUNT; ++k) ls[k*MT + tid] = v[k];
  }
  __syncthreads();

  if (tid == 0) {   // initial dist (virtual source i=0,j=0): EXACT full chain
    ls[T_I0*MT+0] = ls[T_TMEQ0*MT+0];
    ls[T_I1*MT+0] = ls[T_TMEQ1*MT+0];
    double c = ls[T_TMX*MT+0];
    for (int mp = 1; mp <= MM; ++mp) {
      ls[T_I0*MT+mp] = c * ls[T_ENT0*MT+mp];
      ls[T_I1*MT+mp] = c * ls[T_ENT1*MT+mp];
      c *= ls[T_STP*MT+mp];
    }
  }
  __syncthreads();

  for (int i = tid; i < T_COUNT*MT; i += blockDim.x) tabd[i] = ls[i];

  // ---- interleaved emission table: emd[(d*MT+col)*2 + {0:match,1:ins}] ----
  if (tid < NROW) {
    const int m = tid;
    const float* sa = anc  + m*24;
    const float* si = insq + m*24;
    float mxa = -1e30f, mxi = -1e30f;
    for (int d = 0; d < 24; ++d) { mxa = fmaxf(mxa, sa[d]); mxi = fmaxf(mxi, si[d]); }
    float ssa = 0.f, ssi = 0.f;
    for (int d = 0; d < 24; ++d) { ssa += __expf(sa[d]-mxa); ssi += __expf(si[d]-mxi); }
    float ia = 1.f/ssa, ii = 1.f/ssi;
    for (int d = 0; d < 24; ++d) {
      emd[(d*MT+m)*2+0] = (double)(__expf(sa[d]-mxa)*ia);
      emd[(d*MT+m)*2+1] = (double)(__expf(si[d]-mxi)*ii);
    }
    emd[(24*MT+m)*2+0] = 1.0;   // masked token row
    emd[(24*MT+m)*2+1] = 1.0;
  }
  // pad cols 129..131, all 25 token rows
  for (int i = tid; i < 25*3; i += blockDim.x) {
    int d = i/3, c = NROW + i%3;
    emd[(d*MT+c)*2+0] = 0.0;
    emd[(d*MT+c)*2+1] = 0.0;
  }
}

// ---------------------------------------------------------------- fwd -----
// fp64 recurrence (survival window ~beta*M nats -> fp64 mandatory, r5 lesson).
// Delete-chain truncated to k<=1 jumps: raw weight of a k-jump is
// exit*stp_raw^{k-1}*enter with stp_raw ~ e^-10, and an equivalent
// 2-transition route of the same order is always retained -> truncated
// mass <= ~5e-7 relative, far below f32 output ulp. Chain carry is just
// CX = wave_shr(X2). __launch_bounds__(64,1): we need only 2 waves/CU, so
// give the allocator the full VGPR file (avoid AGPR round-trips at VGPR=52).
struct E6 { double2 a, b, c; };

__global__ __launch_bounds__(64, 1)
void fwd_kernel(const double* __restrict__ tabd,
                const double* __restrict__ emd,
                const int* __restrict__ tokoff,
                float* __restrict__ out) {
  __shared__ int ldsT[LSEQ + 8];
  const int lane = threadIdx.x;
  const int n    = blockIdx.x;

  const int* tp = tokoff + n*LSEQ;
  for (int i = lane; i < LSEQ + 8; i += 64)
    ldsT[i] = tp[i < LSEQ ? i : LSEQ-1];

  const int mp0 = 3*lane;
  double tmx[3], tix[3], te0m[3], te0i[3], te1m[3], te1i[3],
         en0[3], en1[3], i0v[3], i1v[3];
#pragma unroll
  for (int j = 0; j < 3; ++j) {
    int mp = mp0 + j;
    bool ok = mp < MT;
    int ix = ok ? mp : 0;
    tmx[j]  = ok ? tabd[T_TMX  *MT+ix] : 0.0;
    tix[j]  = ok ? tabd[T_TIX  *MT+ix] : 0.0;
    te0m[j] = ok ? tabd[T_TMEQ0*MT+ix] : 0.0;
    te0i[j] = ok ? tabd[T_TIEQ0*MT+ix] : 0.0;
    te1m[j] = ok ? tabd[T_TMEQ1*MT+ix] : 0.0;
    te1i[j] = ok ? tabd[T_TIEQ1*MT+ix] : 0.0;
    en0[j]  = ok ? tabd[T_ENT0 *MT+ix] : 0.0;
    en1[j]  = ok ? tabd[T_ENT1 *MT+ix] : 0.0;
    i0v[j]  = ok ? tabd[T_I0   *MT+ix] : 0.0;
    i1v[j]  = ok ? tabd[T_I1   *MT+ix] : 0.0;
  }
  __syncthreads();

  // per-lane emission base (clamped so pad lanes stay in-bounds; their
  // tables are all-zero so the values read are never used)
  const int lx = (lane < 44) ? lane : 43;
  const char* emB = (const char*)emd + (size_t)lx*48;
  auto loadE = [&](int byteOff) {
    E6 e;
    e.a = *(const double2*)(emB + byteOff);
    e.b = *(const double2*)(emB + byteOff + 16);
    e.c = *(const double2*)(emB + byteOff + 32);
    return e;
  };

  // initial alpha (reweighted linear domain, fp64; t=0 uses EXACT init dist)
  double aM0, aM1, aM2, aI0, aI1, aI2;
  {
    E6 e0 = loadE(ldsT[0]);
    aM0 = i0v[0]*e0.a.x;  aI0 = i1v[0]*e0.a.y;
    aM1 = i0v[1]*e0.b.x;  aI1 = i1v[1]*e0.b.y;
    aM2 = i0v[2]*e0.c.x;  aI2 = i1v[2]*e0.c.y;
  }
  int acc2i = 0;

  auto STEP = [&](const E6& cur) {
    const double em0 = cur.a.x, em1 = cur.b.x, em2 = cur.c.x;
    const double ei0 = cur.a.y, ei1 = cur.b.y, ei2 = cur.c.y;

    double ap0 = dpp_d<0x138, 0xF, true>(aM2);   // wave_shr:1, lane0 -> 0
    // off-chain (previous-step state only):
    double X2  = fma(aM1, tmx[2], aI2*tix[2]);   // exit flux at i = mp0+2
    double CX  = dpp_d<0x138, 0xF, true>(X2);    // k=1 carry into next lane
    double X1  = fma(aM0, tmx[1], aI1*tix[1]);
    double e01 = fma(aM0, te0m[1], aI1*te0i[1]);
    double e11 = fma(aM0, te1m[1], aI1*te1i[1]);
    double e02 = fma(aM1, te0m[2], aI2*te0i[2]);
    double e12 = fma(aM1, te1m[2], aI2*te1i[2]);
    // ap0-dependent:
    double e00 = fma(ap0, te0m[0], aI0*te0i[0]);
    double e10 = fma(ap0, te1m[0], aI0*te1i[0]);
    double X0  = fma(ap0, tmx[0], aI0*tix[0]);
    // merge (k<=1 delete jumps only):
    aM0 = fma(CX, en0[0], e00) * em0;
    aI0 = fma(CX, en1[0], e10) * ei0;
    aM1 = fma(X0, en0[1], e01) * em1;
    aI1 = fma(X0, en1[1], e11) * ei1;
    aM2 = fma(X1, en0[2], e02) * em2;
    aI2 = fma(X1, en1[2], e12) * ei2;
  };

  auto RENORM = [&]() {   // exact exponent-only renorm, target max ~= 2^500
    double m = fmax(fmax(fmax(aM0,aM1), fmax(aM2,aI0)), fmax(aI1,aI2));
    m = fmax(m, dpp_d<0x111, 0xF, true >(m));
    m = fmax(m, dpp_d<0x112, 0xF, true >(m));
    m = fmax(m, dpp_d<0x114, 0xF, true >(m));
    m = fmax(m, dpp_d<0x118, 0xF, true >(m));
    m = fmax(m, dpp_d<0x142, 0xA, false>(m));
    m = fmax(m, dpp_d<0x143, 0xC, false>(m));
    int ehi = __builtin_amdgcn_readlane(__double2hiint(m), 63);
    int er  = (ehi >> 20) & 0x7FF;
    int dl  = er ? (1523 - er) : 0;     // multiply by 2^dl -> max ~ 2^500
    acc2i -= dl;
    double sc = __hiloint2double((1023 + dl) << 20, 0);
    aM0 *= sc; aM1 *= sc; aM2 *= sc;
    aI0 *= sc; aI1 *= sc; aI2 *= sc;
  };

  // 17 groups x 15 steps (t = 1..255). 3-deep emission prefetch, and the
  // byte-offset registers themselves prefetched 3 steps further ahead so the
  // LDS-read -> global-load address dependency is never on the hot path.
  E6 bb0 = loadE(ldsT[1]), bb1 = loadE(ldsT[2]), bb2 = loadE(ldsT[3]);
  int of0 = ldsT[4], of1 = ldsT[5], of2 = ldsT[6];
  for (int g = 0; g < 17; ++g) {
    const int tb = 1 + g*15;
#pragma unroll
    for (int k = 0; k < 15; k += 3) {
      STEP(bb0);  bb0 = loadE(of0);  of0 = ldsT[tb + k + 6];
      STEP(bb1);  bb1 = loadE(of1);  of1 = ldsT[tb + k + 7];
      STEP(bb2);  bb2 = loadE(of2);  of2 = ldsT[tb + k + 8];
    }
    RENORM();
  }

  // final: undo reweighting per state (log2 a = log2 a~ + B*log2e*mp + acc2)
  double aMv[3] = {aM0, aM1, aM2}, aIv[3] = {aI0, aI1, aI2};
  double l2[6];
#pragma unroll
  for (int j = 0; j < 3; ++j) {
    double vm = aMv[j], vi = aIv[j];
    double w = BETA * LOG2E * (double)(mp0 + j);
    l2[j]   = (vm > 0.0 ? log2(vm) + w : -1.0e300);
    l2[3+j] = (vi > 0.0 ? log2(vi) + w : -1.0e300);
  }
  double lm = l2[0];
#pragma unroll
  for (int j = 1; j < 6; ++j) lm = fmax(lm, l2[j]);
#pragma unroll
  for (int r = 0; r < 6; ++r) lm = fmax(lm, __shfl_xor(lm, 1 << r));
  lm = fmax(lm, -1.0e280);
  double s = 0.0;
#pragma unroll
  for (int j = 0; j < 6; ++j) s += exp2(l2[j] - lm);
#pragma unroll
  for (int r = 0; r < 6; ++r) s += __shfl_xor(s, 1 << r);
  if (lane == 0) {
    // correction: -255*BETA nats (e^{B t} reweight at t=255)
    out[n] = (float)(LN2*(lm + (double)acc2i + log2(s)) - 255.0*BETA);
  }
}

// ---------------------------------------------------------------- launch --
extern "C" void kernel_launch(void* const* d_in, const int* in_sizes, int n_in,
                              void* d_out, int out_size, void* d_ws, size_t ws_size,
                              hipStream_t stream) {
  const float* anc  = (const float*)d_in[0];
  const float* insq = (const float*)d_in[1];
  const float* rr   = (const float*)d_in[2];
  const float* uu   = (const float*)d_in[3];
  const float* data = (const float*)d_in[4];
  float* out = (float*)d_out;

  int*    tokoff = (int*)d_ws;
  double* tabd   = (double*)((char*)d_ws + TABD_OFF);
  double* emd    = (double*)((char*)d_ws + EMD_OFF);

  hipLaunchKernelGGL(prep_tok_kernel, dim3(1+NSEQ), dim3(LSEQ), 0, stream,
                     anc, insq, rr, uu, data, tabd, emd, tokoff);
  hipLaunchKernelGGL(fwd_kernel,      dim3(NSEQ),   dim3(64),   0, stream,
                     tabd, emd, tokoff, out);
}

// Round 11
// 52.980 us; speedup vs baseline: 1.2718x; 1.2718x over previous
//
#include <hip/hip_runtime.h>

#define MT    132      // padded (M+1): 129 valid + 3 zero pad
#define NSEQ  512
#define LSEQ  256
#define MM    128      // M
#define NROW  129      // M+1
#define BETA  10.0     // reweighting: track a * e^{BETA*(t - mp)}
#define LOG2E 1.4426950408889634
#define LN2   0.6931471805599453

// per-mp transition tables (indexed by i = chain/source index), REWEIGHTED.
// T_W = backward init vector e^{beta*mp} scaled by 2^-923 (fits fp64 exactly).
enum { T_TMX=0, T_TIX, T_TMEQ0, T_TIEQ0, T_TMEQ1, T_TIEQ1,
       T_ENT0, T_ENT1, T_STP, T_I0, T_I1, T_W, T_COUNT };     // 12

// ws layout: [int tokoff NSEQ*LSEQ] [tabd doubles] [emd doubles, 16B-aligned]
#define TOKI_BYTES (NSEQ*LSEQ*4)
#define TABD_OFF   TOKI_BYTES
#define TABD_CNT   (T_COUNT*MT)
#define EMD_OFF    (TABD_OFF + TABD_CNT*8)
#define EMD_ROW_B  (MT*16)                // bytes per token row (col pairs)

// DPP ctrl (gfx9/CDNA): WAVE_SHR1=0x138 (lane l <- l-1; HW-verified r4-r10),
// WAVE_SHL1=0x130 (lane l <- l+1), ROW_SHR:d=0x110+d, ROW_BCAST15/31=0x142/3.
template <int CTRL, int RMASK, bool BC>
__device__ __forceinline__ double dpp_d(double v) {
  int lo = __double2loint(v), hi = __double2hiint(v);
  lo = __builtin_amdgcn_update_dpp(0, lo, CTRL, RMASK, 0xF, BC);
  hi = __builtin_amdgcn_update_dpp(0, hi, CTRL, RMASK, 0xF, BC);
  return __hiloint2double(hi, lo);
}

__device__ __forceinline__ double lse2d(double a, double b) {
  double m = fmax(a, b);
  return m + log(exp(a - m) + exp(b - m));
}

// ---------------------------------------------------------- prep + tok ----
__global__ void prep_tok_kernel(const float* __restrict__ anc,
                                const float* __restrict__ insq,
                                const float* __restrict__ rr,
                                const float* __restrict__ uu,
                                const float* __restrict__ data,
                                double* __restrict__ tabd,
                                double* __restrict__ emd,
                                int* __restrict__ tokoff) {
  const int tid = threadIdx.x;
  if (blockIdx.x != 0) {
    const int n = blockIdx.x - 1;
    const float4* p = (const float4*)(data + (size_t)(n*LSEQ + tid)*24);
    int tok = 24;
#pragma unroll
    for (int q = 0; q < 6; ++q) {
      float4 v = p[q];
      if (v.x > 0.5f) tok = 4*q+0;
      if (v.y > 0.5f) tok = 4*q+1;
      if (v.z > 0.5f) tok = 4*q+2;
      if (v.w > 0.5f) tok = 4*q+3;
    }
    tokoff[n*LSEQ + tid] = tok * EMD_ROW_B;
    return;
  }

  __shared__ double ls[T_COUNT*MT];
  if (tid < MT) {
    double v[T_COUNT];
#pragma unroll
    for (int k = 0; k < T_COUNT; ++k) v[k] = 0.0;
    if (tid <= MM) {
      const int m = tid;
      double rn[3][2], un[3][2];
#pragma unroll
      for (int j = 0; j < 3; ++j) {
        double a0 = (double)rr[(m*3+j)*2+0], a1 = (double)rr[(m*3+j)*2+1];
        double l  = lse2d(a0, a1);
        rn[j][0] = a0 - l; rn[j][1] = a1 - l;
        double b0 = (double)uu[(m*3+j)*2+0], b1 = (double)uu[(m*3+j)*2+1];
        double l2 = lse2d(b0, b1);
        un[j][0] = b0 - l2; un[j][1] = b1 - l2;
      }
      v[T_TMX]   = exp(rn[0][0] + un[0][1] - BETA);
      v[T_TIX]   = exp(rn[1][0] + un[1][1]);
      v[T_TMEQ0] = exp(rn[0][0] + un[0][0]);
      v[T_TIEQ0] = exp(rn[1][0] + un[1][0] + BETA);
      v[T_TMEQ1] = exp(rn[0][1]);
      v[T_TIEQ1] = exp(rn[1][1] + BETA);
      v[T_ENT0]  = exp(rn[2][0] + un[2][0]);
      v[T_ENT1]  = exp(rn[2][1]);
      v[T_STP]   = exp(rn[2][0] + un[2][1] - BETA);
      v[T_W]     = exp2(BETA*LOG2E*(double)m - 923.0);  // e^{beta*mp} * 2^-923
    }
#pragma unroll
    for (int k = 0; k < T_COUNT; ++k) ls[k*MT + tid] = v[k];
  }
  __syncthreads();

  if (tid == 0) {   // initial dist (virtual source i=0,j=0): EXACT full chain
    ls[T_I0*MT+0] = ls[T_TMEQ0*MT+0];
    ls[T_I1*MT+0] = ls[T_TMEQ1*MT+0];
    double c = ls[T_TMX*MT+0];
    for (int mp = 1; mp <= MM; ++mp) {
      ls[T_I0*MT+mp] = c * ls[T_ENT0*MT+mp];
      ls[T_I1*MT+mp] = c * ls[T_ENT1*MT+mp];
      c *= ls[T_STP*MT+mp];
    }
  }
  __syncthreads();

  for (int i = tid; i < T_COUNT*MT; i += blockDim.x) tabd[i] = ls[i];

  // interleaved emission table: emd[(d*MT+col)*2 + {0:match,1:ins}]
  if (tid < NROW) {
    const int m = tid;
    const float* sa = anc  + m*24;
    const float* si = insq + m*24;
    float mxa = -1e30f, mxi = -1e30f;
    for (int d = 0; d < 24; ++d) { mxa = fmaxf(mxa, sa[d]); mxi = fmaxf(mxi, si[d]); }
    float ssa = 0.f, ssi = 0.f;
    for (int d = 0; d < 24; ++d) { ssa += __expf(sa[d]-mxa); ssi += __expf(si[d]-mxi); }
    float ia = 1.f/ssa, ii = 1.f/ssi;
    for (int d = 0; d < 24; ++d) {
      emd[(d*MT+m)*2+0] = (double)(__expf(sa[d]-mxa)*ia);
      emd[(d*MT+m)*2+1] = (double)(__expf(si[d]-mxi)*ii);
    }
    emd[(24*MT+m)*2+0] = 1.0;
    emd[(24*MT+m)*2+1] = 1.0;
  }
  for (int i = tid; i < 25*3; i += blockDim.x) {
    int d = i/3, c = NROW + i%3;
    emd[(d*MT+c)*2+0] = 0.0;
    emd[(d*MT+c)*2+1] = 0.0;
  }
}

// ------------------------------------------------------------- fwd/bwd ----
// Forward-backward split: out = gamma(128)^T alpha(128). Wave 0: 128 forward
// steps (r8-proven k<=5 truncated chain). Wave 1: 127 backward (transpose)
// steps from gamma(255) = e^{beta*mp} (in T_W, pre-scaled 2^-923). Transpose
// chain scan runs down-lane (wave_shl); same locality truncation. Serial
// chain per wave: 255 -> 128 steps.
struct E6 { double2 a, b, c; };

__global__ __launch_bounds__(128)
void fb_kernel(const double* __restrict__ tabd,
               const double* __restrict__ emd,
               const int* __restrict__ tokoff,
               float* __restrict__ out) {
  __shared__ int    ldsT[LSEQ];
  __shared__ double gbuf[64*6];
  __shared__ int    gacc;
  const int tid  = threadIdx.x;
  const int lane = tid & 63;
  const int wid  = tid >> 6;
  const int n    = blockIdx.x;

  const int* tp = tokoff + n*LSEQ;
  for (int i = tid; i < LSEQ; i += 128) ldsT[i] = tp[i];
  __syncthreads();

  const int mp0 = 3*lane;
  const int lx  = (lane < 44) ? lane : 43;
  const char* emB = (const char*)emd + (size_t)lx*48;
  auto loadE = [&](int t) {
    int off = ldsT[t];
    E6 e;
    e.a = *(const double2*)(emB + off);
    e.b = *(const double2*)(emB + off + 16);
    e.c = *(const double2*)(emB + off + 32);
    return e;
  };

  double aM0, aM1, aM2, aI0, aI1, aI2;   // wave0: alpha~; wave1: gamma~
  int acc2i = 0;

  auto RENORM = [&]() {   // exact exponent-only renorm, target max ~= 2^500
    double m = fmax(fmax(fmax(aM0,aM1), fmax(aM2,aI0)), fmax(aI1,aI2));
    m = fmax(m, dpp_d<0x111, 0xF, true >(m));
    m = fmax(m, dpp_d<0x112, 0xF, true >(m));
    m = fmax(m, dpp_d<0x114, 0xF, true >(m));
    m = fmax(m, dpp_d<0x118, 0xF, true >(m));
    m = fmax(m, dpp_d<0x142, 0xA, false>(m));
    m = fmax(m, dpp_d<0x143, 0xC, false>(m));
    int ehi = __builtin_amdgcn_readlane(__double2hiint(m), 63);
    int er  = (ehi >> 20) & 0x7FF;
    int dl  = er ? (1523 - er) : 0;
    acc2i -= dl;
    double sc = __hiloint2double((1023 + dl) << 20, 0);
    aM0 *= sc; aM1 *= sc; aM2 *= sc;
    aI0 *= sc; aI1 *= sc; aI2 *= sc;
  };

  if (wid == 0) {
    // ---------------- forward wave: t = 0 .. 128 ----------------
    double tmx[3], tix[3], te0m[3], te0i[3], te1m[3], te1i[3],
           en0[3], en1[3], stpd[3], i0v[3], i1v[3];
#pragma unroll
    for (int j = 0; j < 3; ++j) {
      int mp = mp0 + j;
      bool ok = mp < MT;
      int ix = ok ? mp : 0;
      tmx[j]  = ok ? tabd[T_TMX  *MT+ix] : 0.0;
      tix[j]  = ok ? tabd[T_TIX  *MT+ix] : 0.0;
      te0m[j] = ok ? tabd[T_TMEQ0*MT+ix] : 0.0;
      te0i[j] = ok ? tabd[T_TIEQ0*MT+ix] : 0.0;
      te1m[j] = ok ? tabd[T_TMEQ1*MT+ix] : 0.0;
      te1i[j] = ok ? tabd[T_TIEQ1*MT+ix] : 0.0;
      en0[j]  = ok ? tabd[T_ENT0 *MT+ix] : 0.0;
      en1[j]  = ok ? tabd[T_ENT1 *MT+ix] : 0.0;
      stpd[j] = ok ? tabd[T_STP  *MT+ix] : 0.0;
      i0v[j]  = ok ? tabd[T_I0   *MT+ix] : 0.0;
      i1v[j]  = ok ? tabd[T_I1   *MT+ix] : 0.0;
    }
    const double stp0  = stpd[0], stp1 = stpd[1];
    const double s2v   = stpd[2];
    const double s12   = stpd[1]*stpd[2];
    const double stp01 = stpd[0]*stpd[1];

    {
      E6 e0 = loadE(0);
      aM0 = i0v[0]*e0.a.x;  aI0 = i1v[0]*e0.a.y;
      aM1 = i0v[1]*e0.b.x;  aI1 = i1v[1]*e0.b.y;
      aM2 = i0v[2]*e0.c.x;  aI2 = i1v[2]*e0.c.y;
    }

    auto STEP = [&](const E6& cur) {          // r8-proven k<=5 truncation
      const double em0 = cur.a.x, em1 = cur.b.x, em2 = cur.c.x;
      const double ei0 = cur.a.y, ei1 = cur.b.y, ei2 = cur.c.y;
      double ap0 = dpp_d<0x138, 0xF, true>(aM2);
      double xi0 = aI0*tix[0], xi1 = aI1*tix[1], xi2 = aI2*tix[2];
      double X1  = fma(aM0, tmx[1], xi1);
      double X2  = fma(aM1, tmx[2], xi2);
      double xx  = fma(X1, s2v, X2);
      double e01 = fma(aM0, te0m[1], aI1*te0i[1]);
      double e02 = fma(aM1, te0m[2], aI2*te0i[2]);
      double e11 = fma(aM0, te1m[1], aI1*te1i[1]);
      double e12 = fma(aM1, te1m[2], aI2*te1i[2]);
      double g02 = en0[2]*em2, q02 = e02*em2;
      double e00 = fma(ap0, te0m[0], aI0*te0i[0]);
      double e10 = fma(ap0, te1m[0], aI0*te1i[0]);
      double X0  = fma(ap0, tmx[0], xi0);
      double x   = fma(X0, s12, xx);
      double pre = fma(X0, stp1, X1);
      double C0  = dpp_d<0x138, 0xF, true>(x);
      double C1  = fma(C0, stp0,  X0);
      double C2  = fma(C0, stp01, pre);
      aM2 = fma(C2, g02, q02);
      aM0 = fma(C0, en0[0], e00) * em0;
      aM1 = fma(C1, en0[1], e01) * em1;
      aI0 = fma(C0, en1[0], e10) * ei0;
      aI1 = fma(C1, en1[1], e11) * ei1;
      aI2 = fma(C2, en1[2], e12) * ei2;
    };

    E6 bb0 = loadE(1), bb1 = loadE(2);
    for (int t = 1; t <= 128; ++t) {
      STEP(bb0);
      bb0 = bb1;
      bb1 = loadE(t + 2);              // t+2 <= 130 < 256: valid, maybe unused
      if ((t & 15) == 0) RENORM();
    }
  } else {
    // ---------------- backward wave: emissions t = 255 .. 129 ----------------
    double en0b[3], en1b[3], stpb[3], ti0b[3], ti1b[3], tixb[3],
           tm0s[3], tm1s[3], tmxs[3];
#pragma unroll
    for (int j = 0; j < 3; ++j) {
      int mp = mp0 + j;
      bool ok  = mp < MT;
      bool okp = mp + 1 < MT;
      int ix  = ok  ? mp     : 0;
      int ixp = okp ? mp + 1 : 0;
      en0b[j] = ok  ? tabd[T_ENT0 *MT+ix ] : 0.0;
      en1b[j] = ok  ? tabd[T_ENT1 *MT+ix ] : 0.0;
      stpb[j] = ok  ? tabd[T_STP  *MT+ix ] : 0.0;
      ti0b[j] = ok  ? tabd[T_TIEQ0*MT+ix ] : 0.0;
      ti1b[j] = ok  ? tabd[T_TIEQ1*MT+ix ] : 0.0;
      tixb[j] = ok  ? tabd[T_TIX  *MT+ix ] : 0.0;
      tm0s[j] = okp ? tabd[T_TMEQ0*MT+ixp] : 0.0;   // tables at index mp+1
      tm1s[j] = okp ? tabd[T_TMEQ1*MT+ixp] : 0.0;
      tmxs[j] = okp ? tabd[T_TMX  *MT+ixp] : 0.0;
      double w = ok ? tabd[T_W    *MT+ix ] : 0.0;   // gamma init e^{b*mp}*2^-923
      if (j == 0) { aM0 = w; aI0 = w; }
      if (j == 1) { aM1 = w; aI1 = w; }
      if (j == 2) { aM2 = w; aI2 = w; }
    }
    acc2i = 923;   // stored gamma = true * 2^-923

    auto BSTEP = [&](const E6& cur) {   // transpose step, k<=5 mirror
      double dM0 = aM0*cur.a.x, dI0 = aI0*cur.a.y;   // delta = em .* gamma
      double dM1 = aM1*cur.b.x, dI1 = aI1*cur.b.y;
      double dM2 = aM2*cur.c.x, dI2 = aI2*cur.c.y;
      double q0 = fma(en0b[0], dM0, en1b[0]*dI0);    // enter-weighted delta
      double q1 = fma(en0b[1], dM1, en1b[1]*dI1);
      double q2 = fma(en0b[2], dM2, en1b[2]*dI2);
      double y  = fma(stpb[0], fma(stpb[1], q2, q1), q0);
      double B  = dpp_d<0x130, 0xF, true>(y);        // wave_shl:1, lane63 -> 0
      double dMn= dpp_d<0x130, 0xF, true>(dM0);
      double dIn= dpp_d<0x130, 0xF, true>(dI0);
      double Q2 = B;                                 // Q[c2] (truncated carry)
      double Q1 = fma(stpb[2], Q2, q2);              // Q[c1]=q[c2]+stp[c2]Q[c2]
      double Q0 = fma(stpb[1], Q1, q1);              // Q[c0]=q[c1]+stp[c1]Q[c1]
      aM0 = fma(tm0s[0], dM1, fma(tm1s[0], dI1, tmxs[0]*Q0));
      aM1 = fma(tm0s[1], dM2, fma(tm1s[1], dI2, tmxs[1]*Q1));
      aM2 = fma(tm0s[2], dMn, fma(tm1s[2], dIn, tmxs[2]*Q2));
      aI0 = fma(ti0b[0], dM0, fma(ti1b[0], dI0, tixb[0]*Q0));
      aI1 = fma(ti0b[1], dM1, fma(ti1b[1], dI1, tixb[1]*Q1));
      aI2 = fma(ti0b[2], dM2, fma(ti1b[2], dI2, tixb[2]*Q2));
    };

    E6 bb0 = loadE(255), bb1 = loadE(254);
    int cnt = 0;
    for (int u = 255; u >= 129; --u) {
      BSTEP(bb0);
      bb0 = bb1;
      bb1 = loadE(u - 2 >= 0 ? u - 2 : 0);
      if (((++cnt) & 15) == 0) RENORM();
    }
    // hand off gamma(128) + exponent
    gbuf[lane*6+0] = aM0;  gbuf[lane*6+1] = aM1;  gbuf[lane*6+2] = aM2;
    gbuf[lane*6+3] = aI0;  gbuf[lane*6+4] = aI1;  gbuf[lane*6+5] = aI2;
    if (lane == 0) gacc = acc2i;
  }
  __syncthreads();

  if (wid == 0) {
    // out = LN2*(log2 sum_s gamma~[s]*alpha~[s] + acc2A + acc2B) - 255*beta
    double av[6] = {aM0, aM1, aM2, aI0, aI1, aI2};
    double l2[6];
#pragma unroll
    for (int j = 0; j < 6; ++j) {
      double g = gbuf[lane*6+j];
      l2[j] = (av[j] > 0.0 && g > 0.0) ? log2(av[j]) + log2(g) : -1.0e300;
    }
    double lm = l2[0];
#pragma unroll
    for (int j = 1; j < 6; ++j) lm = fmax(lm, l2[j]);
#pragma unroll
    for (int r = 0; r < 6; ++r) lm = fmax(lm, __shfl_xor(lm, 1 << r));
    lm = fmax(lm, -1.0e280);
    double s = 0.0;
#pragma unroll
    for (int j = 0; j < 6; ++j) s += exp2(l2[j] - lm);
#pragma unroll
    for (int r = 0; r < 6; ++r) s += __shfl_xor(s, 1 << r);
    if (lane == 0) {
      out[n] = (float)(LN2*(lm + log2(s) + (double)acc2i + (double)gacc)
                       - 255.0*BETA);
    }
  }
}

// ---------------------------------------------------------------- launch --
extern "C" void kernel_launch(void* const* d_in, const int* in_sizes, int n_in,
                              void* d_out, int out_size, void* d_ws, size_t ws_size,
                              hipStream_t stream) {
  const float* anc  = (const float*)d_in[0];
  const float* insq = (const float*)d_in[1];
  const float* rr   = (const float*)d_in[2];
  const float* uu   = (const float*)d_in[3];
  const float* data = (const float*)d_in[4];
  float* out = (float*)d_out;

  int*    tokoff = (int*)d_ws;
  double* tabd   = (double*)((char*)d_ws + TABD_OFF);
  double* emd    = (double*)((char*)d_ws + EMD_OFF);

  hipLaunchKernelGGL(prep_tok_kernel, dim3(1+NSEQ), dim3(LSEQ), 0, stream,
                     anc, insq, rr, uu, data, tabd, emd, tokoff);
  hipLaunchKernelGGL(fb_kernel,       dim3(NSEQ),   dim3(128),  0, stream,
                     tabd, emd, tokoff, out);
}

// Round 12
// 48.546 us; speedup vs baseline: 1.3880x; 1.0913x over previous
//
#include <hip/hip_runtime.h>

#define MT    132      // padded (M+1): 129 valid + 3 zero pad
#define NSEQ  512
#define LSEQ  256
#define MM    128      // M
#define NROW  129      // M+1
#define BETA  10.0     // reweighting: track a * e^{BETA*(t - mp)}
#define LOG2E 1.4426950408889634
#define LN2   0.6931471805599453

// per-mp transition tables (indexed by i = chain/source index), REWEIGHTED.
// T_W = backward init vector e^{beta*mp} scaled by 2^-923 (fits fp64 exactly).
enum { T_TMX=0, T_TIX, T_TMEQ0, T_TIEQ0, T_TMEQ1, T_TIEQ1,
       T_ENT0, T_ENT1, T_STP, T_I0, T_I1, T_W, T_COUNT };     // 12

// ws layout: [tabd doubles][emd doubles]
#define TABD_CNT   (T_COUNT*MT)
#define EMD_OFF    (TABD_CNT*8)
#define EMD_ROW_B  (MT*16)                // bytes per token row (col pairs)

// DPP ctrl (gfx9/CDNA): WAVE_SHR1=0x138 (lane l <- l-1), WAVE_SHL1=0x130
// (lane l <- l+1), ROW_SHR:d=0x110+d, ROW_BCAST15/31=0x142/3.
// All HW-verified rounds 4-11 (absmax 0.0 with these paths live).
template <int CTRL, int RMASK, bool BC>
__device__ __forceinline__ double dpp_d(double v) {
  int lo = __double2loint(v), hi = __double2hiint(v);
  lo = __builtin_amdgcn_update_dpp(0, lo, CTRL, RMASK, 0xF, BC);
  hi = __builtin_amdgcn_update_dpp(0, hi, CTRL, RMASK, 0xF, BC);
  return __hiloint2double(hi, lo);
}

__device__ __forceinline__ double lse2d(double a, double b) {
  double m = fmax(a, b);
  return m + log(exp(a - m) + exp(b - m));
}

// -------------------------------------------------------------- prep ------
// ONE block: transition tables + init dist + interleaved emission table.
__global__ void prep_kernel(const float* __restrict__ anc,
                            const float* __restrict__ insq,
                            const float* __restrict__ rr,
                            const float* __restrict__ uu,
                            double* __restrict__ tabd,
                            double* __restrict__ emd) {
  const int tid = threadIdx.x;
  __shared__ double ls[T_COUNT*MT];
  if (tid < MT) {
    double v[T_COUNT];
#pragma unroll
    for (int k = 0; k < T_COUNT; ++k) v[k] = 0.0;
    if (tid <= MM) {
      const int m = tid;
      double rn[3][2], un[3][2];
#pragma unroll
      for (int j = 0; j < 3; ++j) {
        double a0 = (double)rr[(m*3+j)*2+0], a1 = (double)rr[(m*3+j)*2+1];
        double l  = lse2d(a0, a1);
        rn[j][0] = a0 - l; rn[j][1] = a1 - l;
        double b0 = (double)uu[(m*3+j)*2+0], b1 = (double)uu[(m*3+j)*2+1];
        double l2 = lse2d(b0, b1);
        un[j][0] = b0 - l2; un[j][1] = b1 - l2;
      }
      v[T_TMX]   = exp(rn[0][0] + un[0][1] - BETA);
      v[T_TIX]   = exp(rn[1][0] + un[1][1]);
      v[T_TMEQ0] = exp(rn[0][0] + un[0][0]);
      v[T_TIEQ0] = exp(rn[1][0] + un[1][0] + BETA);
      v[T_TMEQ1] = exp(rn[0][1]);
      v[T_TIEQ1] = exp(rn[1][1] + BETA);
      v[T_ENT0]  = exp(rn[2][0] + un[2][0]);
      v[T_ENT1]  = exp(rn[2][1]);
      v[T_STP]   = exp(rn[2][0] + un[2][1] - BETA);
      v[T_W]     = exp2(BETA*LOG2E*(double)m - 923.0);  // e^{beta*mp} * 2^-923
    }
#pragma unroll
    for (int k = 0; k < T_COUNT; ++k) ls[k*MT + tid] = v[k];
  }
  __syncthreads();

  if (tid == 0) {   // initial dist (virtual source i=0,j=0): EXACT full chain
    ls[T_I0*MT+0] = ls[T_TMEQ0*MT+0];
    ls[T_I1*MT+0] = ls[T_TMEQ1*MT+0];
    double c = ls[T_TMX*MT+0];
    for (int mp = 1; mp <= MM; ++mp) {
      ls[T_I0*MT+mp] = c * ls[T_ENT0*MT+mp];
      ls[T_I1*MT+mp] = c * ls[T_ENT1*MT+mp];
      c *= ls[T_STP*MT+mp];
    }
  }
  __syncthreads();

  for (int i = tid; i < T_COUNT*MT; i += blockDim.x) tabd[i] = ls[i];

  // interleaved emission table: emd[(d*MT+col)*2 + {0:match,1:ins}]
  if (tid < NROW) {
    const int m = tid;
    const float* sa = anc  + m*24;
    const float* si = insq + m*24;
    float mxa = -1e30f, mxi = -1e30f;
    for (int d = 0; d < 24; ++d) { mxa = fmaxf(mxa, sa[d]); mxi = fmaxf(mxi, si[d]); }
    float ssa = 0.f, ssi = 0.f;
    for (int d = 0; d < 24; ++d) { ssa += __expf(sa[d]-mxa); ssi += __expf(si[d]-mxi); }
    float ia = 1.f/ssa, ii = 1.f/ssi;
    for (int d = 0; d < 24; ++d) {
      emd[(d*MT+m)*2+0] = (double)(__expf(sa[d]-mxa)*ia);
      emd[(d*MT+m)*2+1] = (double)(__expf(si[d]-mxi)*ii);
    }
    emd[(24*MT+m)*2+0] = 1.0;
    emd[(24*MT+m)*2+1] = 1.0;
  }
  for (int i = tid; i < 25*3; i += blockDim.x) {
    int d = i/3, c = NROW + i%3;
    emd[(d*MT+c)*2+0] = 0.0;
    emd[(d*MT+c)*2+1] = 0.0;
  }
}

// ------------------------------------------------------------- fwd/bwd ----
// out = gamma(120)^T alpha(120). Wave 0: 120 forward steps (em 1..120,
// 8 groups x 15). Wave 1: 135 backward transpose steps (em 255..121,
// 9 groups x 15) from gamma(255)=e^{beta*mp}*2^-923. Both use r8's proven
// deep pipeline: ring-3 E6 prefetch + byte offsets prefetched 6 ahead.
// Token decode inlined (each block decodes its own 256 positions).
struct E6 { double2 a, b, c; };

__global__ __launch_bounds__(128)
void fb_kernel(const double* __restrict__ tabd,
               const double* __restrict__ emd,
               const float* __restrict__ data,
               float* __restrict__ out) {
  __shared__ int    ldsT[LSEQ];
  __shared__ double gbuf[64*6];
  __shared__ int    gacc;
  const int tid  = threadIdx.x;
  const int lane = tid & 63;
  const int wid  = tid >> 6;
  const int n    = blockIdx.x;

  // inline token decode: 2 positions per thread, float4 loads
  for (int pos = tid; pos < LSEQ; pos += 128) {
    const float4* p = (const float4*)(data + ((size_t)n*LSEQ + pos)*24);
    int tok = 24;
#pragma unroll
    for (int q = 0; q < 6; ++q) {
      float4 v = p[q];
      if (v.x > 0.5f) tok = 4*q+0;
      if (v.y > 0.5f) tok = 4*q+1;
      if (v.z > 0.5f) tok = 4*q+2;
      if (v.w > 0.5f) tok = 4*q+3;
    }
    ldsT[pos] = tok * EMD_ROW_B;
  }
  __syncthreads();

  const int mp0 = 3*lane;
  const int lx  = (lane < 44) ? lane : 43;
  const char* emB = (const char*)emd + (size_t)lx*48;
  auto loadEoff = [&](int off) {
    E6 e;
    e.a = *(const double2*)(emB + off);
    e.b = *(const double2*)(emB + off + 16);
    e.c = *(const double2*)(emB + off + 32);
    return e;
  };

  double aM0, aM1, aM2, aI0, aI1, aI2;   // wave0: alpha~; wave1: gamma~
  int acc2i = 0;

  auto RENORM = [&]() {   // exact exponent-only renorm, target max ~= 2^500
    double m = fmax(fmax(fmax(aM0,aM1), fmax(aM2,aI0)), fmax(aI1,aI2));
    m = fmax(m, dpp_d<0x111, 0xF, true >(m));
    m = fmax(m, dpp_d<0x112, 0xF, true >(m));
    m = fmax(m, dpp_d<0x114, 0xF, true >(m));
    m = fmax(m, dpp_d<0x118, 0xF, true >(m));
    m = fmax(m, dpp_d<0x142, 0xA, false>(m));
    m = fmax(m, dpp_d<0x143, 0xC, false>(m));
    int ehi = __builtin_amdgcn_readlane(__double2hiint(m), 63);
    int er  = (ehi >> 20) & 0x7FF;
    int dl  = er ? (1523 - er) : 0;
    acc2i -= dl;
    double sc = __hiloint2double((1023 + dl) << 20, 0);
    aM0 *= sc; aM1 *= sc; aM2 *= sc;
    aI0 *= sc; aI1 *= sc; aI2 *= sc;
  };

  if (wid == 0) {
    // ---------------- forward wave: em(0) init + steps em 1..120 ----------
    double tmx[3], tix[3], te0m[3], te0i[3], te1m[3], te1i[3],
           en0[3], en1[3], stpd[3], i0v[3], i1v[3];
#pragma unroll
    for (int j = 0; j < 3; ++j) {
      int mp = mp0 + j;
      bool ok = mp < MT;
      int ix = ok ? mp : 0;
      tmx[j]  = ok ? tabd[T_TMX  *MT+ix] : 0.0;
      tix[j]  = ok ? tabd[T_TIX  *MT+ix] : 0.0;
      te0m[j] = ok ? tabd[T_TMEQ0*MT+ix] : 0.0;
      te0i[j] = ok ? tabd[T_TIEQ0*MT+ix] : 0.0;
      te1m[j] = ok ? tabd[T_TMEQ1*MT+ix] : 0.0;
      te1i[j] = ok ? tabd[T_TIEQ1*MT+ix] : 0.0;
      en0[j]  = ok ? tabd[T_ENT0 *MT+ix] : 0.0;
      en1[j]  = ok ? tabd[T_ENT1 *MT+ix] : 0.0;
      stpd[j] = ok ? tabd[T_STP  *MT+ix] : 0.0;
      i0v[j]  = ok ? tabd[T_I0   *MT+ix] : 0.0;
      i1v[j]  = ok ? tabd[T_I1   *MT+ix] : 0.0;
    }
    const double stp0  = stpd[0], stp1 = stpd[1];
    const double s2v   = stpd[2];
    const double s12   = stpd[1]*stpd[2];
    const double stp01 = stpd[0]*stpd[1];

    {
      E6 e0 = loadEoff(ldsT[0]);
      aM0 = i0v[0]*e0.a.x;  aI0 = i1v[0]*e0.a.y;
      aM1 = i0v[1]*e0.b.x;  aI1 = i1v[1]*e0.b.y;
      aM2 = i0v[2]*e0.c.x;  aI2 = i1v[2]*e0.c.y;
    }

    auto STEP = [&](const E6& cur) {          // r8-proven k<=5 truncation
      const double em0 = cur.a.x, em1 = cur.b.x, em2 = cur.c.x;
      const double ei0 = cur.a.y, ei1 = cur.b.y, ei2 = cur.c.y;
      double ap0 = dpp_d<0x138, 0xF, true>(aM2);
      double xi0 = aI0*tix[0], xi1 = aI1*tix[1], xi2 = aI2*tix[2];
      double X1  = fma(aM0, tmx[1], xi1);
      double X2  = fma(aM1, tmx[2], xi2);
      double xx  = fma(X1, s2v, X2);
      double e01 = fma(aM0, te0m[1], aI1*te0i[1]);
      double e02 = fma(aM1, te0m[2], aI2*te0i[2]);
      double e11 = fma(aM0, te1m[1], aI1*te1i[1]);
      double e12 = fma(aM1, te1m[2], aI2*te1i[2]);
      double g02 = en0[2]*em2, q02 = e02*em2;
      double e00 = fma(ap0, te0m[0], aI0*te0i[0]);
      double e10 = fma(ap0, te1m[0], aI0*te1i[0]);
      double X0  = fma(ap0, tmx[0], xi0);
      double x   = fma(X0, s12, xx);
      double pre = fma(X0, stp1, X1);
      double C0  = dpp_d<0x138, 0xF, true>(x);
      double C1  = fma(C0, stp0,  X0);
      double C2  = fma(C0, stp01, pre);
      aM2 = fma(C2, g02, q02);
      aM0 = fma(C0, en0[0], e00) * em0;
      aM1 = fma(C1, en0[1], e01) * em1;
      aI0 = fma(C0, en1[0], e10) * ei0;
      aI1 = fma(C1, en1[1], e11) * ei1;
      aI2 = fma(C2, en1[2], e12) * ei2;
    };

    E6 bb0 = loadEoff(ldsT[1]), bb1 = loadEoff(ldsT[2]), bb2 = loadEoff(ldsT[3]);
    int of0 = ldsT[4], of1 = ldsT[5], of2 = ldsT[6];
    for (int g = 0; g < 8; ++g) {           // 8 x 15 = 120 steps
      const int tb = 1 + g*15;
#pragma unroll
      for (int k = 0; k < 15; k += 3) {
        STEP(bb0);  bb0 = loadEoff(of0);  of0 = ldsT[tb + k + 6];
        STEP(bb1);  bb1 = loadEoff(of1);  of1 = ldsT[tb + k + 7];
        STEP(bb2);  bb2 = loadEoff(of2);  of2 = ldsT[tb + k + 8];
      }
      RENORM();
    }
  } else {
    // ---------------- backward wave: em 255 .. 121 (135 steps) ------------
    double en0b[3], en1b[3], stpb[3], ti0b[3], ti1b[3], tixb[3],
           tm0s[3], tm1s[3], tmxs[3];
#pragma unroll
    for (int j = 0; j < 3; ++j) {
      int mp = mp0 + j;
      bool ok  = mp < MT;
      bool okp = mp + 1 < MT;
      int ix  = ok  ? mp     : 0;
      int ixp = okp ? mp + 1 : 0;
      en0b[j] = ok  ? tabd[T_ENT0 *MT+ix ] : 0.0;
      en1b[j] = ok  ? tabd[T_ENT1 *MT+ix ] : 0.0;
      stpb[j] = ok  ? tabd[T_STP  *MT+ix ] : 0.0;
      ti0b[j] = ok  ? tabd[T_TIEQ0*MT+ix ] : 0.0;
      ti1b[j] = ok  ? tabd[T_TIEQ1*MT+ix ] : 0.0;
      tixb[j] = ok  ? tabd[T_TIX  *MT+ix ] : 0.0;
      tm0s[j] = okp ? tabd[T_TMEQ0*MT+ixp] : 0.0;   // tables at index mp+1
      tm1s[j] = okp ? tabd[T_TMEQ1*MT+ixp] : 0.0;
      tmxs[j] = okp ? tabd[T_TMX  *MT+ixp] : 0.0;
      double w = ok ? tabd[T_W    *MT+ix ] : 0.0;
      if (j == 0) { aM0 = w; aI0 = w; }
      if (j == 1) { aM1 = w; aI1 = w; }
      if (j == 2) { aM2 = w; aI2 = w; }
    }
    acc2i = 923;   // stored gamma = true * 2^-923

    auto BSTEP = [&](const E6& cur) {   // transpose step, r11-proven
      double dM0 = aM0*cur.a.x, dI0 = aI0*cur.a.y;
      double dM1 = aM1*cur.b.x, dI1 = aI1*cur.b.y;
      double dM2 = aM2*cur.c.x, dI2 = aI2*cur.c.y;
      double q0 = fma(en0b[0], dM0, en1b[0]*dI0);
      double q1 = fma(en0b[1], dM1, en1b[1]*dI1);
      double q2 = fma(en0b[2], dM2, en1b[2]*dI2);
      double y  = fma(stpb[0], fma(stpb[1], q2, q1), q0);
      double B  = dpp_d<0x130, 0xF, true>(y);        // wave_shl:1, lane63 -> 0
      double dMn= dpp_d<0x130, 0xF, true>(dM0);
      double dIn= dpp_d<0x130, 0xF, true>(dI0);
      double Q2 = B;
      double Q1 = fma(stpb[2], Q2, q2);
      double Q0 = fma(stpb[1], Q1, q1);
      aM0 = fma(tm0s[0], dM1, fma(tm1s[0], dI1, tmxs[0]*Q0));
      aM1 = fma(tm0s[1], dM2, fma(tm1s[1], dI2, tmxs[1]*Q1));
      aM2 = fma(tm0s[2], dMn, fma(tm1s[2], dIn, tmxs[2]*Q2));
      aI0 = fma(ti0b[0], dM0, fma(ti1b[0], dI0, tixb[0]*Q0));
      aI1 = fma(ti0b[1], dM1, fma(ti1b[1], dI1, tixb[1]*Q1));
      aI2 = fma(ti0b[2], dM2, fma(ti1b[2], dI2, tixb[2]*Q2));
    };

    E6 cc0 = loadEoff(ldsT[255]), cc1 = loadEoff(ldsT[254]), cc2 = loadEoff(ldsT[253]);
    int p0 = ldsT[252], p1 = ldsT[251], p2 = ldsT[250];
    for (int g = 0; g < 9; ++g) {           // 9 x 15 = 135 steps
      const int ub = 255 - g*15;
#pragma unroll
      for (int k = 0; k < 15; k += 3) {
        BSTEP(cc0);  cc0 = loadEoff(p0);  p0 = ldsT[ub - k - 6];
        BSTEP(cc1);  cc1 = loadEoff(p1);  p1 = ldsT[ub - k - 7];
        BSTEP(cc2);  cc2 = loadEoff(p2);  p2 = ldsT[ub - k - 8];
      }
      RENORM();
    }
    // hand off gamma(120) + exponent
    gbuf[lane*6+0] = aM0;  gbuf[lane*6+1] = aM1;  gbuf[lane*6+2] = aM2;
    gbuf[lane*6+3] = aI0;  gbuf[lane*6+4] = aI1;  gbuf[lane*6+5] = aI2;
    if (lane == 0) gacc = acc2i;
  }
  __syncthreads();

  if (wid == 0) {
    double av[6] = {aM0, aM1, aM2, aI0, aI1, aI2};
    double l2[6];
#pragma unroll
    for (int j = 0; j < 6; ++j) {
      double g = gbuf[lane*6+j];
      l2[j] = (av[j] > 0.0 && g > 0.0) ? log2(av[j]) + log2(g) : -1.0e300;
    }
    double lm = l2[0];
#pragma unroll
    for (int j = 1; j < 6; ++j) lm = fmax(lm, l2[j]);
#pragma unroll
    for (int r = 0; r < 6; ++r) lm = fmax(lm, __shfl_xor(lm, 1 << r));
    lm = fmax(lm, -1.0e280);
    double s = 0.0;
#pragma unroll
    for (int j = 0; j < 6; ++j) s += exp2(l2[j] - lm);
#pragma unroll
    for (int r = 0; r < 6; ++r) s += __shfl_xor(s, 1 << r);
    if (lane == 0) {
      out[n] = (float)(LN2*(lm + log2(s) + (double)acc2i + (double)gacc)
                       - 255.0*BETA);
    }
  }
}

// ---------------------------------------------------------------- launch --
extern "C" void kernel_launch(void* const* d_in, const int* in_sizes, int n_in,
                              void* d_out, int out_size, void* d_ws, size_t ws_size,
                              hipStream_t stream) {
  const float* anc  = (const float*)d_in[0];
  const float* insq = (const float*)d_in[1];
  const float* rr   = (const float*)d_in[2];
  const float* uu   = (const float*)d_in[3];
  const float* data = (const float*)d_in[4];
  float* out = (float*)d_out;

  double* tabd = (double*)d_ws;
  double* emd  = (double*)((char*)d_ws + EMD_OFF);

  hipLaunchKernelGGL(prep_kernel, dim3(1),    dim3(256), 0, stream,
                     anc, insq, rr, uu, tabd, emd);
  hipLaunchKernelGGL(fb_kernel,   dim3(NSEQ), dim3(128), 0, stream,
                     tabd, emd, data, out);
}

// Round 13
// 43.013 us; speedup vs baseline: 1.5666x; 1.1286x over previous
//
#include <hip/hip_runtime.h>

#define MT    132      // padded (M+1): 129 valid + 3 zero pad
#define NSEQ  512
#define LSEQ  256
#define MM    128      // M
#define NROW  129      // M+1
#define BETA  10.0     // reweighting: track a * e^{BETA*(t - mp)}
#define LOG2E 1.4426950408889634
#define LN2   0.6931471805599453

// per-mp transition tables (indexed by i = chain/source index), REWEIGHTED.
// T_W = backward init vector e^{beta*mp} scaled by 2^-923 (fits fp64 exactly).
enum { T_TMX=0, T_TIX, T_TMEQ0, T_TIEQ0, T_TMEQ1, T_TIEQ1,
       T_ENT0, T_ENT1, T_STP, T_I0, T_I1, T_W, T_COUNT };     // 12

// ws layout: [tabd doubles][emd doubles]
#define TABD_CNT   (T_COUNT*MT)
#define EMD_OFF    (TABD_CNT*8)
#define EMD_CNT    (2*25*MT)              // 6600 doubles = 52800 B
#define EMD_ROW_B  (MT*16)                // bytes per token row (col pairs)

// DPP ctrl (gfx9/CDNA): WAVE_SHR1=0x138 (lane l <- l-1), WAVE_SHL1=0x130
// (lane l <- l+1), ROW_SHR:d=0x110+d, ROW_BCAST15/31=0x142/3.
// All HW-verified rounds 4-12 (absmax 0.0 with these paths live).
template <int CTRL, int RMASK, bool BC>
__device__ __forceinline__ double dpp_d(double v) {
  int lo = __double2loint(v), hi = __double2hiint(v);
  lo = __builtin_amdgcn_update_dpp(0, lo, CTRL, RMASK, 0xF, BC);
  hi = __builtin_amdgcn_update_dpp(0, hi, CTRL, RMASK, 0xF, BC);
  return __hiloint2double(hi, lo);
}

__device__ __forceinline__ double lse2d(double a, double b) {
  double m = fmax(a, b);
  return m + log(exp(a - m) + exp(b - m));
}

// -------------------------------------------------------------- prep ------
// ONE block: transition tables + init dist + interleaved emission table.
__global__ void prep_kernel(const float* __restrict__ anc,
                            const float* __restrict__ insq,
                            const float* __restrict__ rr,
                            const float* __restrict__ uu,
                            double* __restrict__ tabd,
                            double* __restrict__ emd) {
  const int tid = threadIdx.x;
  __shared__ double ls[T_COUNT*MT];
  if (tid < MT) {
    double v[T_COUNT];
#pragma unroll
    for (int k = 0; k < T_COUNT; ++k) v[k] = 0.0;
    if (tid <= MM) {
      const int m = tid;
      double rn[3][2], un[3][2];
#pragma unroll
      for (int j = 0; j < 3; ++j) {
        double a0 = (double)rr[(m*3+j)*2+0], a1 = (double)rr[(m*3+j)*2+1];
        double l  = lse2d(a0, a1);
        rn[j][0] = a0 - l; rn[j][1] = a1 - l;
        double b0 = (double)uu[(m*3+j)*2+0], b1 = (double)uu[(m*3+j)*2+1];
        double l2 = lse2d(b0, b1);
        un[j][0] = b0 - l2; un[j][1] = b1 - l2;
      }
      v[T_TMX]   = exp(rn[0][0] + un[0][1] - BETA);
      v[T_TIX]   = exp(rn[1][0] + un[1][1]);
      v[T_TMEQ0] = exp(rn[0][0] + un[0][0]);
      v[T_TIEQ0] = exp(rn[1][0] + un[1][0] + BETA);
      v[T_TMEQ1] = exp(rn[0][1]);
      v[T_TIEQ1] = exp(rn[1][1] + BETA);
      v[T_ENT0]  = exp(rn[2][0] + un[2][0]);
      v[T_ENT1]  = exp(rn[2][1]);
      v[T_STP]   = exp(rn[2][0] + un[2][1] - BETA);
      v[T_W]     = exp2(BETA*LOG2E*(double)m - 923.0);  // e^{beta*mp} * 2^-923
    }
#pragma unroll
    for (int k = 0; k < T_COUNT; ++k) ls[k*MT + tid] = v[k];
  }
  __syncthreads();

  if (tid == 0) {   // initial dist (virtual source i=0,j=0): EXACT full chain
    ls[T_I0*MT+0] = ls[T_TMEQ0*MT+0];
    ls[T_I1*MT+0] = ls[T_TMEQ1*MT+0];
    double c = ls[T_TMX*MT+0];
    for (int mp = 1; mp <= MM; ++mp) {
      ls[T_I0*MT+mp] = c * ls[T_ENT0*MT+mp];
      ls[T_I1*MT+mp] = c * ls[T_ENT1*MT+mp];
      c *= ls[T_STP*MT+mp];
    }
  }
  __syncthreads();

  for (int i = tid; i < T_COUNT*MT; i += blockDim.x) tabd[i] = ls[i];

  // interleaved emission table: emd[(d*MT+col)*2 + {0:match,1:ins}]
  if (tid < NROW) {
    const int m = tid;
    const float* sa = anc  + m*24;
    const float* si = insq + m*24;
    float mxa = -1e30f, mxi = -1e30f;
    for (int d = 0; d < 24; ++d) { mxa = fmaxf(mxa, sa[d]); mxi = fmaxf(mxi, si[d]); }
    float ssa = 0.f, ssi = 0.f;
    for (int d = 0; d < 24; ++d) { ssa += __expf(sa[d]-mxa); ssi += __expf(si[d]-mxi); }
    float ia = 1.f/ssa, ii = 1.f/ssi;
    for (int d = 0; d < 24; ++d) {
      emd[(d*MT+m)*2+0] = (double)(__expf(sa[d]-mxa)*ia);
      emd[(d*MT+m)*2+1] = (double)(__expf(si[d]-mxi)*ii);
    }
    emd[(24*MT+m)*2+0] = 1.0;
    emd[(24*MT+m)*2+1] = 1.0;
  }
  for (int i = tid; i < 25*3; i += blockDim.x) {
    int d = i/3, c = NROW + i%3;
    emd[(d*MT+c)*2+0] = 0.0;
    emd[(d*MT+c)*2+1] = 0.0;
  }
}

// ------------------------------------------------------------- fwd/bwd ----
// out = gamma(135)^T alpha(135). Wave 0: 135 forward steps (em 1..135,
// 9 x 15). Wave 1: 120 backward transpose steps (em 255..136, 8 x 15) from
// gamma(255)=e^{beta*mp}*2^-923. EMISSIONS IN LDS (52.8 KB, preloaded once):
// per-step reads become ds_read_b128 with precise lgkmcnt — removes the
// suspected per-step vmcnt(0) L2-latency drain of the global-read path.
struct E6 { double2 a, b, c; };

__global__ __launch_bounds__(128)
void fb_kernel(const double* __restrict__ tabd,
               const double* __restrict__ emd,
               const float* __restrict__ data,
               float* __restrict__ out) {
  __shared__ double ldsE[EMD_CNT];     // 52800 B emission table
  __shared__ int    ldsT[LSEQ];
  __shared__ double gbuf[64*6];
  __shared__ int    gacc;
  const int tid  = threadIdx.x;
  const int lane = tid & 63;
  const int wid  = tid >> 6;
  const int n    = blockIdx.x;

  // preload emission table (double2 coalesced)
  {
    const double2* src = (const double2*)emd;
    double2* dst = (double2*)ldsE;
    for (int i = tid; i < EMD_CNT/2; i += 128) dst[i] = src[i];
  }
  // inline token decode: 2 positions per thread, float4 loads
  for (int pos = tid; pos < LSEQ; pos += 128) {
    const float4* p = (const float4*)(data + ((size_t)n*LSEQ + pos)*24);
    int tok = 24;
#pragma unroll
    for (int q = 0; q < 6; ++q) {
      float4 v = p[q];
      if (v.x > 0.5f) tok = 4*q+0;
      if (v.y > 0.5f) tok = 4*q+1;
      if (v.z > 0.5f) tok = 4*q+2;
      if (v.w > 0.5f) tok = 4*q+3;
    }
    ldsT[pos] = tok * EMD_ROW_B;
  }
  __syncthreads();

  const int mp0 = 3*lane;
  const int lx  = (lane < 44) ? lane : 43;
  const char* lB = (const char*)ldsE + (size_t)lx*48;
  auto loadEoff = [&](int off) {
    E6 e;
    e.a = *(const double2*)(lB + off);
    e.b = *(const double2*)(lB + off + 16);
    e.c = *(const double2*)(lB + off + 32);
    return e;
  };

  double aM0, aM1, aM2, aI0, aI1, aI2;   // wave0: alpha~; wave1: gamma~
  int acc2i = 0;

  auto RENORM = [&]() {   // exact exponent-only renorm, target max ~= 2^500
    double m = fmax(fmax(fmax(aM0,aM1), fmax(aM2,aI0)), fmax(aI1,aI2));
    m = fmax(m, dpp_d<0x111, 0xF, true >(m));
    m = fmax(m, dpp_d<0x112, 0xF, true >(m));
    m = fmax(m, dpp_d<0x114, 0xF, true >(m));
    m = fmax(m, dpp_d<0x118, 0xF, true >(m));
    m = fmax(m, dpp_d<0x142, 0xA, false>(m));
    m = fmax(m, dpp_d<0x143, 0xC, false>(m));
    int ehi = __builtin_amdgcn_readlane(__double2hiint(m), 63);
    int er  = (ehi >> 20) & 0x7FF;
    int dl  = er ? (1523 - er) : 0;
    acc2i -= dl;
    double sc = __hiloint2double((1023 + dl) << 20, 0);
    aM0 *= sc; aM1 *= sc; aM2 *= sc;
    aI0 *= sc; aI1 *= sc; aI2 *= sc;
  };

  if (wid == 0) {
    // ---------------- forward wave: em(0) init + steps em 1..135 ----------
    double tmx[3], tix[3], te0m[3], te0i[3], te1m[3], te1i[3],
           en0[3], en1[3], stpd[3], i0v[3], i1v[3];
#pragma unroll
    for (int j = 0; j < 3; ++j) {
      int mp = mp0 + j;
      bool ok = mp < MT;
      int ix = ok ? mp : 0;
      tmx[j]  = ok ? tabd[T_TMX  *MT+ix] : 0.0;
      tix[j]  = ok ? tabd[T_TIX  *MT+ix] : 0.0;
      te0m[j] = ok ? tabd[T_TMEQ0*MT+ix] : 0.0;
      te0i[j] = ok ? tabd[T_TIEQ0*MT+ix] : 0.0;
      te1m[j] = ok ? tabd[T_TMEQ1*MT+ix] : 0.0;
      te1i[j] = ok ? tabd[T_TIEQ1*MT+ix] : 0.0;
      en0[j]  = ok ? tabd[T_ENT0 *MT+ix] : 0.0;
      en1[j]  = ok ? tabd[T_ENT1 *MT+ix] : 0.0;
      stpd[j] = ok ? tabd[T_STP  *MT+ix] : 0.0;
      i0v[j]  = ok ? tabd[T_I0   *MT+ix] : 0.0;
      i1v[j]  = ok ? tabd[T_I1   *MT+ix] : 0.0;
    }
    const double stp0  = stpd[0], stp1 = stpd[1];
    const double s2v   = stpd[2];
    const double s12   = stpd[1]*stpd[2];
    const double stp01 = stpd[0]*stpd[1];

    {
      E6 e0 = loadEoff(ldsT[0]);
      aM0 = i0v[0]*e0.a.x;  aI0 = i1v[0]*e0.a.y;
      aM1 = i0v[1]*e0.b.x;  aI1 = i1v[1]*e0.b.y;
      aM2 = i0v[2]*e0.c.x;  aI2 = i1v[2]*e0.c.y;
    }

    auto STEP = [&](const E6& cur) {          // r8-proven k<=5 truncation
      const double em0 = cur.a.x, em1 = cur.b.x, em2 = cur.c.x;
      const double ei0 = cur.a.y, ei1 = cur.b.y, ei2 = cur.c.y;
      double ap0 = dpp_d<0x138, 0xF, true>(aM2);
      double xi0 = aI0*tix[0], xi1 = aI1*tix[1], xi2 = aI2*tix[2];
      double X1  = fma(aM0, tmx[1], xi1);
      double X2  = fma(aM1, tmx[2], xi2);
      double xx  = fma(X1, s2v, X2);
      double e01 = fma(aM0, te0m[1], aI1*te0i[1]);
      double e02 = fma(aM1, te0m[2], aI2*te0i[2]);
      double e11 = fma(aM0, te1m[1], aI1*te1i[1]);
      double e12 = fma(aM1, te1m[2], aI2*te1i[2]);
      double g02 = en0[2]*em2, q02 = e02*em2;
      double e00 = fma(ap0, te0m[0], aI0*te0i[0]);
      double e10 = fma(ap0, te1m[0], aI0*te1i[0]);
      double X0  = fma(ap0, tmx[0], xi0);
      double x   = fma(X0, s12, xx);
      double pre = fma(X0, stp1, X1);
      double C0  = dpp_d<0x138, 0xF, true>(x);
      double C1  = fma(C0, stp0,  X0);
      double C2  = fma(C0, stp01, pre);
      aM2 = fma(C2, g02, q02);
      aM0 = fma(C0, en0[0], e00) * em0;
      aM1 = fma(C1, en0[1], e01) * em1;
      aI0 = fma(C0, en1[0], e10) * ei0;
      aI1 = fma(C1, en1[1], e11) * ei1;
      aI2 = fma(C2, en1[2], e12) * ei2;
    };

    E6 bb0 = loadEoff(ldsT[1]), bb1 = loadEoff(ldsT[2]), bb2 = loadEoff(ldsT[3]);
    int of0 = ldsT[4], of1 = ldsT[5], of2 = ldsT[6];
    for (int g = 0; g < 9; ++g) {           // 9 x 15 = 135 steps
      const int tb = 1 + g*15;
#pragma unroll
      for (int k = 0; k < 15; k += 3) {
        STEP(bb0);  bb0 = loadEoff(of0);  of0 = ldsT[tb + k + 6];
        STEP(bb1);  bb1 = loadEoff(of1);  of1 = ldsT[tb + k + 7];
        STEP(bb2);  bb2 = loadEoff(of2);  of2 = ldsT[tb + k + 8];
      }
      RENORM();
    }
  } else {
    // ---------------- backward wave: em 255 .. 136 (120 steps) ------------
    double en0b[3], en1b[3], stpb[3], ti0b[3], ti1b[3], tixb[3],
           tm0s[3], tm1s[3], tmxs[3];
#pragma unroll
    for (int j = 0; j < 3; ++j) {
      int mp = mp0 + j;
      bool ok  = mp < MT;
      bool okp = mp + 1 < MT;
      int ix  = ok  ? mp     : 0;
      int ixp = okp ? mp + 1 : 0;
      en0b[j] = ok  ? tabd[T_ENT0 *MT+ix ] : 0.0;
      en1b[j] = ok  ? tabd[T_ENT1 *MT+ix ] : 0.0;
      stpb[j] = ok  ? tabd[T_STP  *MT+ix ] : 0.0;
      ti0b[j] = ok  ? tabd[T_TIEQ0*MT+ix ] : 0.0;
      ti1b[j] = ok  ? tabd[T_TIEQ1*MT+ix ] : 0.0;
      tixb[j] = ok  ? tabd[T_TIX  *MT+ix ] : 0.0;
      tm0s[j] = okp ? tabd[T_TMEQ0*MT+ixp] : 0.0;   // tables at index mp+1
      tm1s[j] = okp ? tabd[T_TMEQ1*MT+ixp] : 0.0;
      tmxs[j] = okp ? tabd[T_TMX  *MT+ixp] : 0.0;
      double w = ok ? tabd[T_W    *MT+ix ] : 0.0;
      if (j == 0) { aM0 = w; aI0 = w; }
      if (j == 1) { aM1 = w; aI1 = w; }
      if (j == 2) { aM2 = w; aI2 = w; }
    }
    acc2i = 923;   // stored gamma = true * 2^-923

    auto BSTEP = [&](const E6& cur) {   // transpose step, r11-proven
      double dM0 = aM0*cur.a.x, dI0 = aI0*cur.a.y;
      double dM1 = aM1*cur.b.x, dI1 = aI1*cur.b.y;
      double dM2 = aM2*cur.c.x, dI2 = aI2*cur.c.y;
      double q0 = fma(en0b[0], dM0, en1b[0]*dI0);
      double q1 = fma(en0b[1], dM1, en1b[1]*dI1);
      double q2 = fma(en0b[2], dM2, en1b[2]*dI2);
      double y  = fma(stpb[0], fma(stpb[1], q2, q1), q0);
      double B  = dpp_d<0x130, 0xF, true>(y);        // wave_shl:1, lane63 -> 0
      double dMn= dpp_d<0x130, 0xF, true>(dM0);
      double dIn= dpp_d<0x130, 0xF, true>(dI0);
      double Q2 = B;
      double Q1 = fma(stpb[2], Q2, q2);
      double Q0 = fma(stpb[1], Q1, q1);
      aM0 = fma(tm0s[0], dM1, fma(tm1s[0], dI1, tmxs[0]*Q0));
      aM1 = fma(tm0s[1], dM2, fma(tm1s[1], dI2, tmxs[1]*Q1));
      aM2 = fma(tm0s[2], dMn, fma(tm1s[2], dIn, tmxs[2]*Q2));
      aI0 = fma(ti0b[0], dM0, fma(ti1b[0], dI0, tixb[0]*Q0));
      aI1 = fma(ti0b[1], dM1, fma(ti1b[1], dI1, tixb[1]*Q1));
      aI2 = fma(ti0b[2], dM2, fma(ti1b[2], dI2, tixb[2]*Q2));
    };

    E6 cc0 = loadEoff(ldsT[255]), cc1 = loadEoff(ldsT[254]), cc2 = loadEoff(ldsT[253]);
    int p0 = ldsT[252], p1 = ldsT[251], p2 = ldsT[250];
    for (int g = 0; g < 8; ++g) {           // 8 x 15 = 120 steps
      const int ub = 255 - g*15;
#pragma unroll
      for (int k = 0; k < 15; k += 3) {
        BSTEP(cc0);  cc0 = loadEoff(p0);  p0 = ldsT[ub - k - 6];
        BSTEP(cc1);  cc1 = loadEoff(p1);  p1 = ldsT[ub - k - 7];
        BSTEP(cc2);  cc2 = loadEoff(p2);  p2 = ldsT[ub - k - 8];
      }
      RENORM();
    }
    // hand off gamma(135) + exponent
    gbuf[lane*6+0] = aM0;  gbuf[lane*6+1] = aM1;  gbuf[lane*6+2] = aM2;
    gbuf[lane*6+3] = aI0;  gbuf[lane*6+4] = aI1;  gbuf[lane*6+5] = aI2;
    if (lane == 0) gacc = acc2i;
  }
  __syncthreads();

  if (wid == 0) {
    double av[6] = {aM0, aM1, aM2, aI0, aI1, aI2};
    double l2[6];
#pragma unroll
    for (int j = 0; j < 6; ++j) {
      double g = gbuf[lane*6+j];
      l2[j] = (av[j] > 0.0 && g > 0.0) ? log2(av[j]) + log2(g) : -1.0e300;
    }
    double lm = l2[0];
#pragma unroll
    for (int j = 1; j < 6; ++j) lm = fmax(lm, l2[j]);
#pragma unroll
    for (int r = 0; r < 6; ++r) lm = fmax(lm, __shfl_xor(lm, 1 << r));
    lm = fmax(lm, -1.0e280);
    double s = 0.0;
#pragma unroll
    for (int j = 0; j < 6; ++j) s += exp2(l2[j] - lm);
#pragma unroll
    for (int r = 0; r < 6; ++r) s += __shfl_xor(s, 1 << r);
    if (lane == 0) {
      out[n] = (float)(LN2*(lm + log2(s) + (double)acc2i + (double)gacc)
                       - 255.0*BETA);
    }
  }
}

// ---------------------------------------------------------------- launch --
extern "C" void kernel_launch(void* const* d_in, const int* in_sizes, int n_in,
                              void* d_out, int out_size, void* d_ws, size_t ws_size,
                              hipStream_t stream) {
  const float* anc  = (const float*)d_in[0];
  const float* insq = (const float*)d_in[1];
  const float* rr   = (const float*)d_in[2];
  const float* uu   = (const float*)d_in[3];
  const float* data = (const float*)d_in[4];
  float* out = (float*)d_out;

  double* tabd = (double*)d_ws;
  double* emd  = (double*)((char*)d_ws + EMD_OFF);

  hipLaunchKernelGGL(prep_kernel, dim3(1),    dim3(256), 0, stream,
                     anc, insq, rr, uu, tabd, emd);
  hipLaunchKernelGGL(fb_kernel,   dim3(NSEQ), dim3(128), 0, stream,
                     tabd, emd, data, out);
}